// Round 4
// baseline (231.492 us; speedup 1.0000x reference)
//
#include <hip/hip_runtime.h>

// NTXentLoss, B=8192, D=128, T=0.1, idx=0. fp32 in, fp32 scalar out.
// R10: break the acc WAR serialization. R9 (~38 us inferred) epilogue(t)
// reads acc while MFMA(t+1) rewrites the SAME regs -> per-wave VALU/MFMA
// serialize; waves barrier-lockstep into the same phase (convoy).
// Now: per tile, 4 column-granules {4 ds_read + 8 MFMA -> accCur} with the
// PREVIOUS granule's epilogue (exp/mask/add into rs) interleaved; accA/accB
// ping-pong (static names, rule #20) removes the WAR chain -> compiler can
// put epilogue VALU in the MFMA shadow. acc VGPR 32->16 (~105 total, under
// the 128 2-block cliff). ilab -> LDS (4 KB, once/block), jlab -> 8 regs:
// no VMEM in the loop except stage loads -> vmcnt(0) == "stage(t+1) done".
// posfinal fused via last-block ticket (threadfence + agent atomics).

#define BB 8192
#define DD 128
#define TM 128
#define TN 128
#define NJ 8

typedef __attribute__((ext_vector_type(8))) short short8;
typedef __attribute__((ext_vector_type(4))) float floatx4;

#define GLOBAL_AS __attribute__((address_space(1)))
#define LDS_AS    __attribute__((address_space(3)))

static __device__ __forceinline__ float wave_sum(float v) {
#pragma unroll
    for (int off = 32; off > 0; off >>= 1) v += __shfl_xor(v, off, 64);
    return v;
}

static __device__ __forceinline__ unsigned short f2bf(float f) {
    unsigned int u = __float_as_uint(f);
    return (unsigned short)((u + 0x7FFFu + ((u >> 16) & 1u)) >> 16);
}

// ---- prep: normalize rows -> bf16 + 1/norm; zero denom/out/tickets -------
__global__ __launch_bounds__(256) void prep_kernel(
    const float* __restrict__ zis, const float* __restrict__ zjs,
    unsigned short* __restrict__ Zib, unsigned short* __restrict__ Zjb,
    float* __restrict__ rni, float* __restrict__ rnj,
    float* __restrict__ denom, int* __restrict__ tickets,
    float* __restrict__ out, int nout)
{
    if (threadIdx.x < 2) denom[blockIdx.x * 2 + threadIdx.x] = 0.0f;
    if (blockIdx.x == 0 && (int)threadIdx.x < nout) out[threadIdx.x] = 0.0f;
    if (blockIdx.x == 2 && threadIdx.x < 64) tickets[threadIdx.x] = 0;

    int wave = threadIdx.x >> 6, lane = threadIdx.x & 63;
    int row = blockIdx.x * 4 + wave;
    const float* src; unsigned short* dst; float* rn; int r;
    if (row < BB) { src = zis; dst = Zib; rn = rni; r = row; }
    else          { src = zjs; dst = Zjb; rn = rnj; r = row - BB; }
    float2 u = *(const float2*)(src + (size_t)r * DD + lane * 2);
    float s = wave_sum(u.x * u.x + u.y * u.y);
    float sc = 1.0f / sqrtf(s);
    if (lane == 0) rn[r] = sc;
    ushort2 o; o.x = f2bf(u.x * sc); o.y = f2bf(u.y * sc);
    *(ushort2*)(dst + (size_t)r * DD + lane * 2) = o;
}

// ---- j-streaming MFMA kernel, 8 waves (4x2), wave tile 32x64 -------------
// LDS B: row n (256 B), phys 16-B slot p holds logical k-slot s = p^(n&15)
// (inverse swizzle on per-lane GLOBAL source, rule #21; gload_lds dest
// linear). ds_read_b128: 2 lanes / 16-B granule -> 2-way = free (m136).
__global__ __launch_bounds__(512, 2) void mfma_tile_kernel(
    const unsigned short* __restrict__ Zjb,   // A: zj normalized (rows i)
    const unsigned short* __restrict__ Zib,   // B: zi normalized (cols j)
    const int* __restrict__ ilab, const int* __restrict__ jlab,
    float* __restrict__ denom, int* __restrict__ tickets,
    const float* __restrict__ zis, const float* __restrict__ zjs,
    const float* __restrict__ rni, const float* __restrict__ rnj,
    const float* __restrict__ wts, const int* __restrict__ idxp,
    float* __restrict__ out)
{
    __shared__ __align__(16) unsigned short Bt[2][TN * DD];   // 64 KB
    __shared__ int ilds[NJ * TN];                             // 4 KB
    __shared__ int tkt;
    __shared__ float part[8];

    int tid  = threadIdx.x;
    int lane = tid & 63, wave = tid >> 6;     // 8 waves
    int wm = wave >> 1, wn = wave & 1;        // 4x2 grid, 32x64 each
    int quad = lane >> 4, l15 = lane & 15;
    int i0    = blockIdx.y * TM;
    int jbase = blockIdx.x * (NJ * TN);

    // all 1024 i-labels for this block's j-range -> LDS (once)
    ilds[tid]       = ilab[jbase + tid];
    ilds[tid + 512] = ilab[jbase + tid + 512];

    // j-labels for my 8 output rows -> registers (block-constant)
    int jrv[8];
#pragma unroll
    for (int mt = 0; mt < 2; ++mt)
#pragma unroll
        for (int r = 0; r < 4; ++r)
            jrv[mt * 4 + r] = jlab[i0 + wm * 32 + mt * 16 + quad * 4 + r];

    // A fragments -> registers (32 VGPR): row = wm*32+mt*16+l15, k = ks*32+quad*8
    short8 af[2][4];
#pragma unroll
    for (int mt = 0; mt < 2; ++mt)
#pragma unroll
        for (int ks = 0; ks < 4; ++ks)
            af[mt][ks] = *(const short8*)(Zjb
                + (size_t)(i0 + wm * 32 + mt * 16 + l15) * DD
                + ks * 32 + quad * 8);

    // staging: 32 regions x 1 KB; 4 global_load_lds per wave
    int rl = lane >> 4, p = lane & 15;
    auto stage = [&](int t) {
        const unsigned short* src = Zib + (size_t)(jbase + t * TN) * DD;
        unsigned short* lb = &Bt[t & 1][0];
#pragma unroll
        for (int u = 0; u < 4; ++u) {
            int g = wave * 4 + u;
            int grow = g * 4 + rl;
            int gslot = p ^ (grow & 15);
            const unsigned short* gp = src + (size_t)grow * DD + gslot * 8;
            unsigned short* lp = lb + g * 512;
            __builtin_amdgcn_global_load_lds((const GLOBAL_AS void*)gp,
                                             (LDS_AS void*)lp, 16, 0, 0);
        }
    };

    float rs[2][4];
#pragma unroll
    for (int mt = 0; mt < 2; ++mt)
#pragma unroll
        for (int r = 0; r < 4; ++r) rs[mt][r] = 0.0f;

    // granule: 4 ds_read + 8 MFMA into aC (fresh accumulate)
    auto gran = [&](const unsigned short* bb, int nt, floatx4 (&aC)[2]) {
        int n = wn * 64 + nt * 16 + l15;
#pragma unroll
        for (int ks = 0; ks < 4; ++ks) {
            int ps = (((ks << 2) | quad) ^ l15) << 3;   // phys slot * 8
            short8 b = *(const short8*)(bb + n * DD + ps);
            if (ks == 0) {
                floatx4 zz = (floatx4){0.f, 0.f, 0.f, 0.f};
                aC[0] = __builtin_amdgcn_mfma_f32_16x16x32_bf16(af[0][0], b, zz, 0, 0, 0);
                aC[1] = __builtin_amdgcn_mfma_f32_16x16x32_bf16(af[1][0], b, zz, 0, 0, 0);
            } else {
                aC[0] = __builtin_amdgcn_mfma_f32_16x16x32_bf16(af[0][ks], b, aC[0], 0, 0, 0);
                aC[1] = __builtin_amdgcn_mfma_f32_16x16x32_bf16(af[1][ks], b, aC[1], 0, 0, 0);
            }
        }
    };
    // epilogue of a finished granule: exp + mask + accumulate (pure VALU)
    auto epi = [&](floatx4 (&aP)[2], int ilP) {
#pragma unroll
        for (int mt = 0; mt < 2; ++mt)
#pragma unroll
            for (int r = 0; r < 4; ++r) {
                float e = __expf(fmaf(aP[mt][r], 10.0f, -10.0f));
                rs[mt][r] += (ilP != jrv[mt * 4 + r]) ? e : 0.0f;
            }
    };

    floatx4 accA[2], accB[2];
    // sentinel: exp(fmaf(-1e30,10,-10)) underflows to 0 -> first epi adds 0
    accB[0] = (floatx4){-1e30f, -1e30f, -1e30f, -1e30f};
    accB[1] = accB[0];
    int ilB = 0;

    stage(0);
    stage(1);
    // pending VMEM: af(8)+jrv(8)+ilds(2)+stage0(4)+stage1(4); vmcnt(4)
    // leaves stage(1) in flight; lgkmcnt(0) fences ilds ds_writes.
    asm volatile("s_waitcnt vmcnt(4) lgkmcnt(0)" ::: "memory");
    __builtin_amdgcn_s_barrier();

#pragma unroll 2
    for (int t = 0; t < NJ; ++t) {
        const unsigned short* bb = &Bt[t & 1][0];
        const int* ilr = &ilds[t * TN + wn * 64 + l15];
        __builtin_amdgcn_s_setprio(1);
        gran(bb, 0, accA); int il0 = ilr[0];  epi(accB, ilB);   // prev tile g3
        gran(bb, 1, accB); int il1 = ilr[16]; epi(accA, il0);
        gran(bb, 2, accA); int il2 = ilr[32]; epi(accB, il1);
        gran(bb, 3, accB); ilB = ilr[48];     epi(accA, il2);
        __builtin_amdgcn_s_setprio(0);
        // accB (g3) epilogue deferred into next tile -> overlaps barrier.
        if (t + 1 < NJ) {
            // only stage(t+1)'s 4 loads pending (labels are LDS/regs now)
            asm volatile("s_waitcnt vmcnt(0)" ::: "memory");
            __builtin_amdgcn_s_barrier();
            if (t + 2 < NJ) stage(t + 2);
        }
    }
    epi(accB, ilB);   // flush

    // ---- reduce over l15 + one atomic round per block --------------------
#pragma unroll
    for (int mt = 0; mt < 2; ++mt)
#pragma unroll
        for (int r = 0; r < 4; ++r) {
            float v = rs[mt][r];
            v += __shfl_xor(v, 1, 64);
            v += __shfl_xor(v, 2, 64);
            v += __shfl_xor(v, 4, 64);
            v += __shfl_xor(v, 8, 64);
            if (l15 == 0)
                atomicAdd(&denom[i0 + wm * 32 + mt * 16 + quad * 4 + r], v);
        }

    // ---- last-block ticket: fuse pos+finalize for this i0 group ----------
    __threadfence();          // release: denom atomics visible device-wide
    __syncthreads();
    if (tid == 0) tkt = atomicAdd(&tickets[blockIdx.y], 1);
    __syncthreads();
    if (tkt == 7) {           // all 8 j-panel blocks for i0 are done
        __threadfence();      // acquire
        int idx2 = idxp[0];
        float ll = 0.0f;
#pragma unroll 4
        for (int rr = 0; rr < 16; ++rr) {
            int i = i0 + wave * 16 + rr;
            int j = idx2 + i;
            float2 a  = *(const float2*)(zjs + (size_t)i * DD + lane * 2);
            float2 b2 = *(const float2*)(zis + (size_t)j * DD + lane * 2);
            float s = wave_sum(a.x * b2.x + a.y * b2.y);
            if (lane == 0) {
                float d = __hip_atomic_load(&denom[i], __ATOMIC_RELAXED,
                                            __HIP_MEMORY_SCOPE_AGENT);
                float pp = s * rni[j] * rnj[i] * 10.0f;
                float l = 10.0f + logf(__expf(pp - 10.0f) + d) - pp;
                float w = wts[j];
                ll += (l * w) / w;    // faithful to reference's weighted mean
            }
        }
        if (lane == 0) part[wave] = ll;
        __syncthreads();
        if (tid == 0) {
            float sum = 0.0f;
#pragma unroll
            for (int q = 0; q < 8; ++q) sum += part[q];
            atomicAdd(out, sum * (1.0f / BB));
        }
    }
}

// ---- launch --------------------------------------------------------------
extern "C" void kernel_launch(void* const* d_in, const int* in_sizes, int n_in,
                              void* d_out, int out_size, void* d_ws, size_t ws_size,
                              hipStream_t stream) {
    const float* zis = (const float*)d_in[0];
    const float* zjs = (const float*)d_in[1];
    const int* ilab = (const int*)d_in[2];
    const int* jlab = (const int*)d_in[3];
    const float* wts = (const float*)d_in[4];
    const int* idxp = (const int*)d_in[5];
    float* out = (float*)d_out;

    float* rni   = (float*)d_ws;
    float* rnj   = rni + BB;
    float* denom = rnj + BB;
    int*   tickets = (int*)(denom + BB);                  // 64 ints
    unsigned short* Zib = (unsigned short*)(tickets + 64); // [BB][DD] bf16
    unsigned short* Zjb = Zib + (size_t)BB * DD;

    prep_kernel<<<2 * BB / 4, 256, 0, stream>>>(
        zis, zjs, Zib, Zjb, rni, rnj, denom, tickets, out, out_size);
    mfma_tile_kernel<<<dim3(BB / (NJ * TN), BB / TM), 512, 0, stream>>>(
        Zjb, Zib, ilab, jlab, denom, tickets,
        zis, zjs, rni, rnj, wts, idxp, out);
}

// Round 5
// 116.511 us; speedup vs baseline: 1.9869x; 1.9869x over previous
//
#include <hip/hip_runtime.h>

// NTXentLoss, B=8192, D=128, T=0.1, idx=0. fp32 in, fp32 scalar out.
// R11: revert R10's ticket fusion. R10's 180us was a serialized fence tail:
// per-block __threadfence() (agent scope) on gfx950 = cross-XCD L2
// writeback/invalidate (buffer_wbl2/buffer_inv); 512 blocks x 8 waves of
// those serialized at TCC -> all pipes idle, occupancy 13%. Separate
// posfinal kernel restored (R9 structure). KEPT from R10 (clean A/B of the
// acc-WAR theory): granule interleave with accA/accB ping-pong (epilogue
// of granule g-1 scheduled into MFMA shadow of granule g), ilab->LDS,
// jlab->regs (in-loop VMEM = stage loads only, vmcnt counting exact).

#define BB 8192
#define DD 128
#define TM 128
#define TN 128
#define NJ 8

typedef __attribute__((ext_vector_type(8))) short short8;
typedef __attribute__((ext_vector_type(4))) float floatx4;

#define GLOBAL_AS __attribute__((address_space(1)))
#define LDS_AS    __attribute__((address_space(3)))

static __device__ __forceinline__ float wave_sum(float v) {
#pragma unroll
    for (int off = 32; off > 0; off >>= 1) v += __shfl_xor(v, off, 64);
    return v;
}

static __device__ __forceinline__ unsigned short f2bf(float f) {
    unsigned int u = __float_as_uint(f);
    return (unsigned short)((u + 0x7FFFu + ((u >> 16) & 1u)) >> 16);
}

// ---- prep: normalize rows -> bf16 + 1/norm; zero denom/out ---------------
__global__ __launch_bounds__(256) void prep_kernel(
    const float* __restrict__ zis, const float* __restrict__ zjs,
    unsigned short* __restrict__ Zib, unsigned short* __restrict__ Zjb,
    float* __restrict__ rni, float* __restrict__ rnj,
    float* __restrict__ denom, float* __restrict__ out, int nout)
{
    if (threadIdx.x < 2) denom[blockIdx.x * 2 + threadIdx.x] = 0.0f;
    if (blockIdx.x == 0 && (int)threadIdx.x < nout) out[threadIdx.x] = 0.0f;

    int wave = threadIdx.x >> 6, lane = threadIdx.x & 63;
    int row = blockIdx.x * 4 + wave;
    const float* src; unsigned short* dst; float* rn; int r;
    if (row < BB) { src = zis; dst = Zib; rn = rni; r = row; }
    else          { src = zjs; dst = Zjb; rn = rnj; r = row - BB; }
    float2 u = *(const float2*)(src + (size_t)r * DD + lane * 2);
    float s = wave_sum(u.x * u.x + u.y * u.y);
    float sc = 1.0f / sqrtf(s);
    if (lane == 0) rn[r] = sc;
    ushort2 o; o.x = f2bf(u.x * sc); o.y = f2bf(u.y * sc);
    *(ushort2*)(dst + (size_t)r * DD + lane * 2) = o;
}

// ---- j-streaming MFMA kernel, 8 waves (4x2), wave tile 32x64 -------------
// LDS B: row n (256 B), phys 16-B slot p holds logical k-slot s = p^(n&15)
// (inverse swizzle on per-lane GLOBAL source, rule #21; gload_lds dest
// linear). ds_read_b128: 2 lanes / 16-B granule -> 2-way = free (m136).
__global__ __launch_bounds__(512, 2) void mfma_tile_kernel(
    const unsigned short* __restrict__ Zjb,   // A: zj normalized (rows i)
    const unsigned short* __restrict__ Zib,   // B: zi normalized (cols j)
    const int* __restrict__ ilab, const int* __restrict__ jlab,
    float* __restrict__ denom)
{
    __shared__ __align__(16) unsigned short Bt[2][TN * DD];   // 64 KB
    __shared__ int ilds[NJ * TN];                             // 4 KB

    int tid  = threadIdx.x;
    int lane = tid & 63, wave = tid >> 6;     // 8 waves
    int wm = wave >> 1, wn = wave & 1;        // 4x2 grid, 32x64 each
    int quad = lane >> 4, l15 = lane & 15;
    int i0    = blockIdx.y * TM;
    int jbase = blockIdx.x * (NJ * TN);

    // all 1024 i-labels for this block's j-range -> LDS (once)
    ilds[tid]       = ilab[jbase + tid];
    ilds[tid + 512] = ilab[jbase + tid + 512];

    // j-labels for my 8 output rows -> registers (block-constant)
    int jrv[8];
#pragma unroll
    for (int mt = 0; mt < 2; ++mt)
#pragma unroll
        for (int r = 0; r < 4; ++r)
            jrv[mt * 4 + r] = jlab[i0 + wm * 32 + mt * 16 + quad * 4 + r];

    // A fragments -> registers (32 VGPR): row = wm*32+mt*16+l15, k = ks*32+quad*8
    short8 af[2][4];
#pragma unroll
    for (int mt = 0; mt < 2; ++mt)
#pragma unroll
        for (int ks = 0; ks < 4; ++ks)
            af[mt][ks] = *(const short8*)(Zjb
                + (size_t)(i0 + wm * 32 + mt * 16 + l15) * DD
                + ks * 32 + quad * 8);

    // staging: 32 regions x 1 KB; 4 global_load_lds per wave
    int rl = lane >> 4, p = lane & 15;
    auto stage = [&](int t) {
        const unsigned short* src = Zib + (size_t)(jbase + t * TN) * DD;
        unsigned short* lb = &Bt[t & 1][0];
#pragma unroll
        for (int u = 0; u < 4; ++u) {
            int g = wave * 4 + u;
            int grow = g * 4 + rl;
            int gslot = p ^ (grow & 15);
            const unsigned short* gp = src + (size_t)grow * DD + gslot * 8;
            unsigned short* lp = lb + g * 512;
            __builtin_amdgcn_global_load_lds((const GLOBAL_AS void*)gp,
                                             (LDS_AS void*)lp, 16, 0, 0);
        }
    };

    float rs[2][4];
#pragma unroll
    for (int mt = 0; mt < 2; ++mt)
#pragma unroll
        for (int r = 0; r < 4; ++r) rs[mt][r] = 0.0f;

    // granule: 4 ds_read + 8 MFMA into aC (fresh accumulate)
    auto gran = [&](const unsigned short* bb, int nt, floatx4 (&aC)[2]) {
        int n = wn * 64 + nt * 16 + l15;
#pragma unroll
        for (int ks = 0; ks < 4; ++ks) {
            int ps = (((ks << 2) | quad) ^ l15) << 3;   // phys slot * 8
            short8 b = *(const short8*)(bb + n * DD + ps);
            if (ks == 0) {
                floatx4 zz = (floatx4){0.f, 0.f, 0.f, 0.f};
                aC[0] = __builtin_amdgcn_mfma_f32_16x16x32_bf16(af[0][0], b, zz, 0, 0, 0);
                aC[1] = __builtin_amdgcn_mfma_f32_16x16x32_bf16(af[1][0], b, zz, 0, 0, 0);
            } else {
                aC[0] = __builtin_amdgcn_mfma_f32_16x16x32_bf16(af[0][ks], b, aC[0], 0, 0, 0);
                aC[1] = __builtin_amdgcn_mfma_f32_16x16x32_bf16(af[1][ks], b, aC[1], 0, 0, 0);
            }
        }
    };
    // epilogue of a finished granule: exp + mask + accumulate (pure VALU)
    auto epi = [&](floatx4 (&aP)[2], int ilP) {
#pragma unroll
        for (int mt = 0; mt < 2; ++mt)
#pragma unroll
            for (int r = 0; r < 4; ++r) {
                float e = __expf(fmaf(aP[mt][r], 10.0f, -10.0f));
                rs[mt][r] += (ilP != jrv[mt * 4 + r]) ? e : 0.0f;
            }
    };

    floatx4 accA[2], accB[2];
    // sentinel: exp(fmaf(-1e30,10,-10)) underflows to 0 -> first epi adds 0
    accB[0] = (floatx4){-1e30f, -1e30f, -1e30f, -1e30f};
    accB[1] = accB[0];
    int ilB = 0;

    stage(0);
    stage(1);
    // vmcnt(4) leaves stage(1)'s 4 loads in flight; everything older
    // (af/jrv/ilds-src/stage(0)) has landed. lgkmcnt(0) fences ilds writes.
    asm volatile("s_waitcnt vmcnt(4) lgkmcnt(0)" ::: "memory");
    __builtin_amdgcn_s_barrier();

#pragma unroll 2
    for (int t = 0; t < NJ; ++t) {
        const unsigned short* bb = &Bt[t & 1][0];
        const int* ilr = &ilds[t * TN + wn * 64 + l15];
        __builtin_amdgcn_s_setprio(1);
        gran(bb, 0, accA); int il0 = ilr[0];  epi(accB, ilB);   // prev tile g3
        gran(bb, 1, accB); int il1 = ilr[16]; epi(accA, il0);
        gran(bb, 2, accA); int il2 = ilr[32]; epi(accB, il1);
        gran(bb, 3, accB); ilB = ilr[48];     epi(accA, il2);
        __builtin_amdgcn_s_setprio(0);
        // accB (g3) epilogue deferred into next tile -> overlaps barrier.
        if (t + 1 < NJ) {
            // only stage(t+1)'s 4 loads pending here
            asm volatile("s_waitcnt vmcnt(0)" ::: "memory");
            __builtin_amdgcn_s_barrier();
            if (t + 2 < NJ) stage(t + 2);
        }
    }
    epi(accB, ilB);   // flush

    // ---- reduce over l15 + one atomic round per block --------------------
#pragma unroll
    for (int mt = 0; mt < 2; ++mt)
#pragma unroll
        for (int r = 0; r < 4; ++r) {
            float v = rs[mt][r];
            v += __shfl_xor(v, 1, 64);
            v += __shfl_xor(v, 2, 64);
            v += __shfl_xor(v, 4, 64);
            v += __shfl_xor(v, 8, 64);
            if (l15 == 0)
                atomicAdd(&denom[i0 + wm * 32 + mt * 16 + quad * 4 + r], v);
        }
}

// ---- fused pos + finalize (512 blocks, 4 rows/wave, 1 atomic/block) ------
__global__ __launch_bounds__(256) void posfinal_kernel(
    const float* __restrict__ zis, const float* __restrict__ zjs,
    const float* __restrict__ rni, const float* __restrict__ rnj,
    const float* __restrict__ denom, const float* __restrict__ wts,
    const int* __restrict__ idxp, float* __restrict__ out)
{
    int wave = threadIdx.x >> 6, lane = threadIdx.x & 63;
    int idx = idxp[0];
    float ll = 0.0f;
#pragma unroll
    for (int t = 0; t < 4; ++t) {
        int i = blockIdx.x * 16 + wave * 4 + t;
        int j = idx + i;
        float2 a  = *(const float2*)(zjs + (size_t)i * DD + lane * 2);
        float2 b2 = *(const float2*)(zis + (size_t)j * DD + lane * 2);
        float s = wave_sum(a.x * b2.x + a.y * b2.y);
        if (lane == 0) {
            float p = s * rni[j] * rnj[i] * 10.0f;
            float l = 10.0f + logf(__expf(p - 10.0f) + denom[i]) - p;
            float w = wts[j];
            ll += (l * w) / w;    // faithful to reference's weighted mean
        }
    }
    __shared__ float part[4];
    if (lane == 0) part[wave] = ll;
    __syncthreads();
    if (threadIdx.x == 0)
        atomicAdd(out, (part[0] + part[1] + part[2] + part[3]) * (1.0f / BB));
}

// ---- launch --------------------------------------------------------------
extern "C" void kernel_launch(void* const* d_in, const int* in_sizes, int n_in,
                              void* d_out, int out_size, void* d_ws, size_t ws_size,
                              hipStream_t stream) {
    const float* zis = (const float*)d_in[0];
    const float* zjs = (const float*)d_in[1];
    const int* ilab = (const int*)d_in[2];
    const int* jlab = (const int*)d_in[3];
    const float* wts = (const float*)d_in[4];
    const int* idxp = (const int*)d_in[5];
    float* out = (float*)d_out;

    float* rni   = (float*)d_ws;
    float* rnj   = rni + BB;
    float* denom = rnj + BB;
    unsigned short* Zib = (unsigned short*)(denom + BB);  // [BB][DD] bf16
    unsigned short* Zjb = Zib + (size_t)BB * DD;

    prep_kernel<<<2 * BB / 4, 256, 0, stream>>>(
        zis, zjs, Zib, Zjb, rni, rnj, denom, out, out_size);
    mfma_tile_kernel<<<dim3(BB / (NJ * TN), BB / TM), 512, 0, stream>>>(
        Zjb, Zib, ilab, jlab, denom);
    posfinal_kernel<<<BB / 16, 256, 0, stream>>>(
        zis, zjs, rni, rnj, denom, wts, idxp, out);
}